// Round 3
// baseline (1916.707 us; speedup 1.0000x reference)
//
#include <hip/hip_runtime.h>
#include <hip/hip_bf16.h>
#include <stdint.h>

typedef __bf16 bf;
typedef __bf16 bfv8 __attribute__((ext_vector_type(8)));
typedef __bf16 bfv4 __attribute__((ext_vector_type(4)));
typedef float  f32x4 __attribute__((ext_vector_type(4)));

#define MFMA16(a,b,c) __builtin_amdgcn_mfma_f32_16x16x32_bf16((a),(b),(c),0,0,0)

#define CH  96
#define WID 256
#define HGT 256
#define NB  8
#define SCALE 0.1020620726159658f   // 96^-0.5

__device__ __forceinline__ float b2f(bf x){ return (float)x; }
__device__ __forceinline__ bf   f2b(float x){ return (bf)x; }

__device__ __forceinline__ bfv8 ld_cvt8(const float* __restrict__ p){
  f32x4 a = *(const f32x4*)p;
  f32x4 b = *(const f32x4*)(p + 4);
  bfv8 r;
  r[0]=f2b(a[0]); r[1]=f2b(a[1]); r[2]=f2b(a[2]); r[3]=f2b(a[3]);
  r[4]=f2b(b[0]); r[5]=f2b(b[1]); r[6]=f2b(b[2]); r[7]=f2b(b[3]);
  return r;
}

// ---------------- K1: fused conv1x1 (MFMA) + depthwise 3x3 ----------------
// output tile 64x2, halo 66x4 = 264 pixels in LDS, stride 96 (no pad) = 50,688 B -> 3 blocks/CU
#define TW 64
#define TH 2
#define HC 66
#define HROWS 264
#define TSTR 96

__global__ __launch_bounds__(256) void k_proj(
    const float* __restrict__ X, const float* __restrict__ W1, const float* __restrict__ B1,
    const float* __restrict__ WD, const float* __restrict__ BD, bf* __restrict__ O)
{
  extern __shared__ bf tile[];  // [264][96]
  const int tid = threadIdx.x;
  const int lane = tid & 63, wid = tid >> 6;
  const int l15 = lane & 15, lg = lane >> 4;
  const int gx = blockIdx.x * TW;
  const int gy = blockIdx.y * TH;
  const int b  = blockIdx.z;
  const size_t ibase = (size_t)b * (HGT*WID) * CH;

  bfv8 wf[6][3];
#pragma unroll
  for (int nt=0; nt<6; ++nt)
#pragma unroll
    for (int ks=0; ks<3; ++ks)
      wf[nt][ks] = ld_cvt8(W1 + (nt*16 + l15)*CH + ks*32 + lg*8);
  float bias[6];
#pragma unroll
  for (int nt=0; nt<6; ++nt) bias[nt] = B1[nt*16 + l15];

  // Phase A: conv1x1 over halo pixels -> LDS (zeros outside image = SAME pad)
  for (int mt = wid; mt < 17; mt += 4) {
    int p = mt*16 + l15;
    int hr = p / HC, hcc = p % HC;
    int y = gy - 1 + hr, x = gx - 1 + hcc;
    bool inb = (p < HROWS) & (y >= 0) & (y < HGT) & (x >= 0) & (x < WID);
    bfv8 af[3];
#pragma unroll
    for (int ks=0; ks<3; ++ks) {
      bfv8 v = {0,0,0,0,0,0,0,0};
      if (inb) v = ld_cvt8(X + ibase + ((size_t)y*WID + x)*CH + ks*32 + lg*8);
      af[ks] = v;
    }
    f32x4 acc[6];
#pragma unroll
    for (int nt=0; nt<6; ++nt) acc[nt] = (f32x4){bias[nt],bias[nt],bias[nt],bias[nt]};
#pragma unroll
    for (int ks=0; ks<3; ++ks)
#pragma unroll
      for (int nt=0; nt<6; ++nt)
        acc[nt] = MFMA16(af[ks], wf[nt][ks], acc[nt]);
    int prow = mt*16 + lg*4;
#pragma unroll
    for (int r=0; r<4; ++r) {
      int pp = prow + r;
      if (pp < HROWS) {
        int hr2 = pp / HC, hc2 = pp % HC;
        int yy = gy - 1 + hr2, xx = gx - 1 + hc2;
        bool ib = (yy >= 0) & (yy < HGT) & (xx >= 0) & (xx < WID);
#pragma unroll
        for (int nt=0; nt<6; ++nt)
          tile[pp*TSTR + nt*16 + l15] = f2b(ib ? acc[nt][r] : 0.f);
      }
    }
  }
  __syncthreads();

  // Phase B: depthwise 3x3 from LDS
  if (tid < 252) {
    int g = tid % 12;        // channel octet 0..11
    int pi0 = tid / 12;      // 0..20
    float w9[8][9], bb[8];
#pragma unroll
    for (int j=0;j<8;++j) {
#pragma unroll
      for (int t=0;t<9;++t) w9[j][t] = WD[(g*8+j)*9 + t];
      bb[j] = BD[g*8+j];
    }
    for (int pi = pi0; pi < TW*TH; pi += 21) {
      int oy = pi / TW, ox = pi % TW;
      int y = gy + oy;
      float acc[8];
#pragma unroll
      for (int j=0;j<8;++j) acc[j] = bb[j];
#pragma unroll
      for (int dy=0; dy<3; ++dy)
#pragma unroll
        for (int dx=0; dx<3; ++dx) {
          bfv8 v8 = *(const bfv8*)(tile + ((oy+dy)*HC + (ox+dx))*TSTR + g*8);
#pragma unroll
          for (int j=0;j<8;++j) acc[j] += w9[j][dy*3+dx] * b2f(v8[j]);
        }
      bf* dst = O + (size_t)b*(HGT*WID)*CH + ((size_t)y*WID + gx + ox)*CH + g*8;
      bfv8 st;
#pragma unroll
      for (int j=0;j<8;++j) st[j] = f2b(acc[j]);
      *(bfv8*)dst = st;
    }
  }
}

// ---------------- K_vt: in-place per-(b,h)-row transpose [v][c] -> [c][v] ----------------
__global__ __launch_bounds__(256) void k_vt(bf* Vl, bf* Vr)
{
  __shared__ bf vt2[96*264];  // 50,688 B
  const int tid = threadIdx.x, lane = tid & 63, wid = tid >> 6;
  bf* V = (blockIdx.y ? Vr : Vl) + (size_t)blockIdx.x * (WID*CH);
  {
    const bfv8* src = (const bfv8*)(V + (size_t)tid*CH);
#pragma unroll
    for (int i=0;i<12;++i){ bfv8 v8 = src[i];
#pragma unroll
      for (int j=0;j<8;++j) vt2[(i*8+j)*264 + tid] = v8[j]; }
  }
  __syncthreads();   // all reads done before in-place overwrite
  for (int c = wid; c < CH; c += 4)
    *(bfv4*)(V + c*WID + lane*4) = *(const bfv4*)(vt2 + c*264 + lane*4);
}

// ---------------- K_attn: fused scores+softmax+apply, both directions ----------------
// one block per (b,h); LDS = A-quarter bounce [64][264] + rowsum[256] = 34,816 B
// phase 0 (r2l): S = Ql Qr^T, A = softmax_v(S)*scale, F_r2l = A @ Vr   (rows = w)
// phase 1 (l2r): S^T = Qr Ql^T, A^T via exp(S^T)*scale/rowsum[w], F_l2r = A^T @ Vl (rows = v)
// F written interleaved into d_out as bf16: pixel p -> [p*192 + side*96 + c]
__global__ __launch_bounds__(256) void k_attn(
    const bf* __restrict__ Ql, const bf* __restrict__ Qr,
    const bf* __restrict__ Vlt, const bf* __restrict__ Vrt,
    bf* __restrict__ Fout)
{
  extern __shared__ char sm[];
  bf* aq = (bf*)sm;                       // [64][264]
  float* rs = (float*)(sm + 64*264*2);    // [256]
  const int tid=threadIdx.x, lane=tid&63, wid=tid>>6;
  const int l15=lane&15, lg=lane>>4;
  const int bh = blockIdx.x;
  const size_t qoff = (size_t)bh * (WID*CH);
  float fw[16];

#pragma unroll 1
  for (int phase=0; phase<2; ++phase) {
    const bf* msrc = phase ? Qr + qoff : Ql + qoff;
    const bf* nsrc = phase ? Ql + qoff : Qr + qoff;
    const bf* vt   = (phase ? Vlt : Vrt) + qoff;
    const int outoff = phase ? CH : 0;
    if (phase) {
      __syncthreads();       // rowsums complete
#pragma unroll
      for (int nt=0;nt<16;++nt) fw[nt] = SCALE / rs[nt*16+l15];
    }
#pragma unroll 1
    for (int q=0;q<4;++q) {
      const int m0 = q*64 + wid*16;
      // ---- scores tile [16 m-rows][256 n] ----
      bfv8 af[3];
#pragma unroll
      for (int ks=0;ks<3;++ks)
        af[ks] = *(const bfv8*)(msrc + (size_t)(m0+l15)*CH + ks*32 + lg*8);
      f32x4 acc[16];
#pragma unroll
      for (int nt=0;nt<16;++nt) acc[nt]=(f32x4){0.f,0.f,0.f,0.f};
#pragma unroll
      for (int ks=0;ks<3;++ks)
#pragma unroll
        for (int nt=0;nt<16;++nt)
          acc[nt] = MFMA16(af[ks],
              *(const bfv8*)(nsrc + (size_t)(nt*16+l15)*CH + ks*32+lg*8), acc[nt]);
      // ---- softmax transform -> bounce into aq (wave-private rows) ----
      if (phase==0) {
        float rsum[4]={0.f,0.f,0.f,0.f};
#pragma unroll
        for (int nt=0;nt<16;++nt)
#pragma unroll
          for (int r=0;r<4;++r){ float e=__expf(acc[nt][r]); acc[nt][r]=e; rsum[r]+=e; }
#pragma unroll
        for (int off=1; off<16; off<<=1)
#pragma unroll
          for (int r=0;r<4;++r) rsum[r] += __shfl_xor(rsum[r], off, 64);
        if (l15==0){
#pragma unroll
          for (int r=0;r<4;++r) rs[m0 + lg*4 + r] = rsum[r];
        }
        float sc[4];
#pragma unroll
        for (int r=0;r<4;++r) sc[r] = SCALE / rsum[r];
#pragma unroll
        for (int nt=0;nt<16;++nt)
#pragma unroll
          for (int r=0;r<4;++r)
            aq[(wid*16+lg*4+r)*264 + nt*16+l15] = f2b(acc[nt][r]*sc[r]);
      } else {
#pragma unroll
        for (int nt=0;nt<16;++nt)
#pragma unroll
          for (int r=0;r<4;++r)
            aq[(wid*16+lg*4+r)*264 + nt*16+l15] = f2b(__expf(acc[nt][r])*fw[nt]);
      }
      // ---- apply GEMM: [16 rows] x [k=256] x [96 c], B from transposed V (global/L2) ----
      f32x4 o[6];
#pragma unroll
      for (int nt=0;nt<6;++nt) o[nt]=(f32x4){0.f,0.f,0.f,0.f};
#pragma unroll
      for (int ks=0;ks<8;++ks) {
        bfv8 aa = *(const bfv8*)(aq + (wid*16+l15)*264 + ks*32 + lg*8);
#pragma unroll
        for (int nt=0;nt<6;++nt)
          o[nt] = MFMA16(aa,
              *(const bfv8*)(vt + (size_t)(nt*16+l15)*WID + ks*32+lg*8), o[nt]);
      }
#pragma unroll
      for (int nt=0;nt<6;++nt){
        int c = nt*16+l15;
#pragma unroll
        for (int r=0;r<4;++r){
          size_t p = (size_t)bh*WID + m0 + lg*4 + r;
          Fout[p*192 + outoff + c] = f2b(o[nt][r]);
        }
      }
    }
  }
}

// ---------------- K3: u = x + scale*(conv1x1(F)+b); out = down(u1,u2) ----------------
// 64 pixels/block, LDS 26,624 B -> 6 blocks/CU. F read from d_out (bf16), OUT written over it.
__global__ __launch_bounds__(256) void k_fuse(
    const float* __restrict__ I1, const float* __restrict__ I2,
    const bf* F,
    const float* __restrict__ LW, const float* __restrict__ LB,
    const float* __restrict__ RW, const float* __restrict__ RB,
    const float* __restrict__ DWN, const float* __restrict__ DBN,
    const float* __restrict__ BETA, const float* __restrict__ GAMMA,
    float* OUT)
{
  extern __shared__ bf us[];   // u1 [64][104], u2 [64][104]
  bf* u1 = us;
  bf* u2 = us + 64*104;
  const int tid=threadIdx.x, lane=tid&63, wid=tid>>6;
  const int l15=lane&15, lg=lane>>4;
  const size_t p0 = (size_t)blockIdx.x * 64;

#pragma unroll
  for (int side=0; side<2; ++side) {
    const float* Wp = side ? RW : LW;
    const float* Bp = side ? RB : LB;
    const float* X  = side ? I2 : I1;
    const float* SC = side ? GAMMA : BETA;
    bf* u = side ? u2 : u1;
    bfv8 wf[6][3];
#pragma unroll
    for (int nt=0;nt<6;++nt)
#pragma unroll
      for (int ks=0;ks<3;++ks)
        wf[nt][ks] = ld_cvt8(Wp + (nt*16+l15)*CH + ks*32 + lg*8);
    float bias[6], scl[6];
#pragma unroll
    for (int nt=0;nt<6;++nt){ bias[nt]=Bp[nt*16+l15]; scl[nt]=SC[nt*16+l15]; }
    bfv8 af[3];
#pragma unroll
    for (int ks=0;ks<3;++ks)
      af[ks] = *(const bfv8*)(F + (p0 + wid*16 + l15)*192 + side*96 + ks*32 + lg*8);
    f32x4 acc[6];
#pragma unroll
    for (int nt=0;nt<6;++nt) acc[nt]=(f32x4){bias[nt],bias[nt],bias[nt],bias[nt]};
#pragma unroll
    for (int ks=0;ks<3;++ks)
#pragma unroll
      for (int nt=0;nt<6;++nt) acc[nt] = MFMA16(af[ks], wf[nt][ks], acc[nt]);
    int pr = wid*16 + lg*4;
#pragma unroll
    for (int nt=0;nt<6;++nt) {
      int c = nt*16 + l15;
#pragma unroll
      for (int r=0;r<4;++r) {
        float xv = X[(p0+pr+r)*CH + c];
        u[(pr+r)*104 + c] = f2b(xv + scl[nt]*acc[nt][r]);
      }
    }
  }
  __syncthreads();
  float bias[6];
#pragma unroll
  for (int nt=0;nt<6;++nt) bias[nt]=DBN[nt*16+l15];
  bfv8 a1[3], a2[3];
#pragma unroll
  for (int ks=0;ks<3;++ks) {
    a1[ks] = *(const bfv8*)(u1 + (wid*16+l15)*104 + ks*32 + lg*8);
    a2[ks] = *(const bfv8*)(u2 + (wid*16+l15)*104 + ks*32 + lg*8);
  }
  f32x4 acc[6];
#pragma unroll
  for (int nt=0;nt<6;++nt) acc[nt]=(f32x4){bias[nt],bias[nt],bias[nt],bias[nt]};
#pragma unroll
  for (int ks=0;ks<3;++ks)
#pragma unroll
    for (int nt=0;nt<6;++nt) {
      bfv8 w1 = ld_cvt8(DWN + (nt*16+l15)*192 + ks*32 + lg*8);
      bfv8 w2 = ld_cvt8(DWN + (nt*16+l15)*192 + 96 + ks*32 + lg*8);
      acc[nt] = MFMA16(a1[ks], w1, acc[nt]);
      acc[nt] = MFMA16(a2[ks], w2, acc[nt]);
    }
  int pr = wid*16 + lg*4;
#pragma unroll
  for (int nt=0;nt<6;++nt) {
    int c = nt*16 + l15;
#pragma unroll
    for (int r=0;r<4;++r)
      OUT[(p0+pr+r)*CH + c] = acc[nt][r];
  }
}

extern "C" void kernel_launch(void* const* d_in, const int* in_sizes, int n_in,
                              void* d_out, int out_size, void* d_ws, size_t ws_size,
                              hipStream_t stream)
{
  (void)in_sizes; (void)n_in; (void)out_size; (void)ws_size;
  const float* I1 = (const float*)d_in[0];
  const float* I2 = (const float*)d_in[1];
  const float* se1_w = (const float*)d_in[4];
  const float* se1_b = (const float*)d_in[5];
  const float* se1_dw= (const float*)d_in[6];
  const float* se1_db= (const float*)d_in[7];
  const float* se2_w = (const float*)d_in[8];
  const float* se2_b = (const float*)d_in[9];
  const float* se2_dw= (const float*)d_in[10];
  const float* se2_db= (const float*)d_in[11];
  const float* lp1_w = (const float*)d_in[12];
  const float* lp1_b = (const float*)d_in[13];
  const float* lp1_dw= (const float*)d_in[14];
  const float* lp1_db= (const float*)d_in[15];
  const float* rp1_w = (const float*)d_in[16];
  const float* rp1_b = (const float*)d_in[17];
  const float* rp1_dw= (const float*)d_in[18];
  const float* rp1_db= (const float*)d_in[19];
  const float* lp2_w = (const float*)d_in[20];
  const float* lp2_b = (const float*)d_in[21];
  const float* rp2_w = (const float*)d_in[22];
  const float* rp2_b = (const float*)d_in[23];
  const float* down_w= (const float*)d_in[24];
  const float* down_b= (const float*)d_in[25];
  const float* beta  = (const float*)d_in[26];
  const float* gamma = (const float*)d_in[27];
  float* OUT = (float*)d_out;
  bf* Fbuf = (bf*)d_out;   // interleaved F, exactly fills the 192MB out buffer

  const size_t FIELD = (size_t)NB * HGT * WID * CH;
  bf* Ql = (bf*)d_ws;
  bf* Qr = Ql + FIELD;
  bf* Vl = Qr + FIELD;     // becomes Vl^T after k_vt (in-place)
  bf* Vr = Vl + FIELD;     // becomes Vr^T

  dim3 blk(256,1,1);
  k_proj<<<dim3(4,128,NB), blk, HROWS*TSTR*2, stream>>>(I1, se1_w, se1_b, se1_dw, se1_db, Ql);
  k_proj<<<dim3(4,128,NB), blk, HROWS*TSTR*2, stream>>>(I2, se2_w, se2_b, se2_dw, se2_db, Qr);
  k_proj<<<dim3(4,128,NB), blk, HROWS*TSTR*2, stream>>>(I1, lp1_w, lp1_b, lp1_dw, lp1_db, Vl);
  k_proj<<<dim3(4,128,NB), blk, HROWS*TSTR*2, stream>>>(I2, rp1_w, rp1_b, rp1_dw, rp1_db, Vr);
  k_vt<<<dim3(NB*HGT,2,1), blk, 0, stream>>>(Vl, Vr);
  k_attn<<<dim3(NB*HGT,1,1), blk, 64*264*2 + 256*4, stream>>>(Ql, Qr, Vl, Vr, Fbuf);
  k_fuse<<<dim3(8192,1,1), blk, 2*64*104*2, stream>>>(I1, I2, Fbuf,
        lp2_w, lp2_b, rp2_w, rp2_b, down_w, down_b, beta, gamma, OUT);
}

// Round 4
// 1677.566 us; speedup vs baseline: 1.1426x; 1.1426x over previous
//
#include <hip/hip_runtime.h>
#include <hip/hip_bf16.h>
#include <stdint.h>

typedef __bf16 bf;
typedef __bf16 bfv8 __attribute__((ext_vector_type(8)));
typedef __bf16 bfv4 __attribute__((ext_vector_type(4)));
typedef float  f32x4 __attribute__((ext_vector_type(4)));

#define MFMA16(a,b,c) __builtin_amdgcn_mfma_f32_16x16x32_bf16((a),(b),(c),0,0,0)

#define CH  96
#define WID 256
#define HGT 256
#define NB  8
#define SCALE 0.1020620726159658f   // 96^-0.5

__device__ __forceinline__ float b2f(bf x){ return (float)x; }
__device__ __forceinline__ bf   f2b(float x){ return (bf)x; }

__device__ __forceinline__ bfv8 ld_cvt8(const float* __restrict__ p){
  f32x4 a = *(const f32x4*)p;
  f32x4 b = *(const f32x4*)(p + 4);
  bfv8 r;
  r[0]=f2b(a[0]); r[1]=f2b(a[1]); r[2]=f2b(a[2]); r[3]=f2b(a[3]);
  r[4]=f2b(b[0]); r[5]=f2b(b[1]); r[6]=f2b(b[2]); r[7]=f2b(b[3]);
  return r;
}

// ---------------- K1: dual fused conv1x1 (MFMA) + depthwise 3x3 ----------------
// Computes TWO projections of the same input X, sharing the X halo loads (held
// in registers across both passes). Output tile 64x2, halo 66x4 = 264 rows.
#define TW 64
#define TH 2
#define HC 66
#define HROWS 264
#define TSTR 96

__global__ __launch_bounds__(256) void k_proj2(
    const float* __restrict__ X,
    const float* __restrict__ W1a, const float* __restrict__ B1a,
    const float* __restrict__ WDa, const float* __restrict__ BDa, bf* __restrict__ Oa,
    const float* __restrict__ W1b, const float* __restrict__ B1b,
    const float* __restrict__ WDb, const float* __restrict__ BDb, bf* __restrict__ Ob)
{
  extern __shared__ bf tile[];  // [264][96] = 50,688 B
  const int tid=threadIdx.x, lane=tid&63, wid=tid>>6;
  const int l15=lane&15, lg=lane>>4;
  const int gx=blockIdx.x*TW, gy=blockIdx.y*TH, b=blockIdx.z;
  const size_t ibase=(size_t)b*(HGT*WID)*CH;

  // X halo A-frags, loaded ONCE, reused by both projection passes
  bfv8 af[5][3];
#pragma unroll
  for (int i=0;i<5;++i){
    int mt=wid+i*4;
    int p=mt*16+l15;
    int hr=p/HC, hcc=p%HC;
    int y=gy-1+hr, x=gx-1+hcc;
    bool inb=(mt<17)&&(p<HROWS)&&(y>=0)&&(y<HGT)&&(x>=0)&&(x<WID);
#pragma unroll
    for (int ks=0;ks<3;++ks){
      bfv8 v={0,0,0,0,0,0,0,0};
      if (inb) v=ld_cvt8(X+ibase+((size_t)y*WID+x)*CH+ks*32+lg*8);
      af[i][ks]=v;
    }
  }

#pragma unroll 1
  for (int pass=0; pass<2; ++pass){
    const float* W1 = pass?W1b:W1a;
    const float* B1 = pass?B1b:B1a;
    const float* WD = pass?WDb:WDa;
    const float* BD = pass?BDb:BDa;
    bf* O = pass?Ob:Oa;
    if (pass) __syncthreads();   // pass-0 phase-B tile reads done before overwrite
    {
      bfv8 wf[6][3];
      float bias[6];
#pragma unroll
      for (int nt=0;nt<6;++nt){
        bias[nt]=B1[nt*16+l15];
#pragma unroll
        for (int ks=0;ks<3;++ks) wf[nt][ks]=ld_cvt8(W1+(nt*16+l15)*CH+ks*32+lg*8);
      }
#pragma unroll
      for (int i=0;i<5;++i){
        int mt=wid+i*4;
        if (mt>=17) continue;
        f32x4 acc[6];
#pragma unroll
        for (int nt=0;nt<6;++nt) acc[nt]=(f32x4){bias[nt],bias[nt],bias[nt],bias[nt]};
#pragma unroll
        for (int ks=0;ks<3;++ks)
#pragma unroll
          for (int nt=0;nt<6;++nt) acc[nt]=MFMA16(af[i][ks],wf[nt][ks],acc[nt]);
        int prow=mt*16+lg*4;
#pragma unroll
        for (int r=0;r<4;++r){
          int pp=prow+r;
          if (pp<HROWS){
            int hr2=pp/HC,hc2=pp%HC;
            int yy=gy-1+hr2, xx=gx-1+hc2;
            bool ib=(yy>=0)&&(yy<HGT)&&(xx>=0)&&(xx<WID);
#pragma unroll
            for (int nt=0;nt<6;++nt) tile[pp*TSTR+nt*16+l15]=f2b(ib?acc[nt][r]:0.f);
          }
        }
      }
    }
    __syncthreads();
    // depthwise 3x3 from LDS
    if (tid<252){
      int g=tid%12, pi0=tid/12;
      float w9[8][9], bb[8];
#pragma unroll
      for (int j=0;j<8;++j){
#pragma unroll
        for (int t=0;t<9;++t) w9[j][t]=WD[(g*8+j)*9+t];
        bb[j]=BD[g*8+j];
      }
      for (int pi=pi0; pi<TW*TH; pi+=21){
        int oy=pi/TW, ox=pi%TW;
        int y=gy+oy;
        float acc[8];
#pragma unroll
        for (int j=0;j<8;++j) acc[j]=bb[j];
#pragma unroll
        for (int dy=0;dy<3;++dy)
#pragma unroll
          for (int dx=0;dx<3;++dx){
            bfv8 v8=*(const bfv8*)(tile+((oy+dy)*HC+(ox+dx))*TSTR+g*8);
#pragma unroll
            for (int j=0;j<8;++j) acc[j]+=w9[j][dy*3+dx]*b2f(v8[j]);
          }
        bf* dst=O+ibase+((size_t)y*WID+gx+ox)*CH+g*8;
        bfv8 st;
#pragma unroll
        for (int j=0;j<8;++j) st[j]=f2b(acc[j]);
        *(bfv8*)dst=st;
      }
    }
  }
}

// ---------------- K_vt: in-place per-(b,h)-row transpose [v][c] -> [c][v] ----------------
__global__ __launch_bounds__(256) void k_vt(bf* Vl, bf* Vr)
{
  __shared__ bf vt2[96*264];  // 50,688 B
  const int tid = threadIdx.x, lane = tid & 63, wid = tid >> 6;
  bf* V = (blockIdx.y ? Vr : Vl) + (size_t)blockIdx.x * (WID*CH);
  {
    const bfv8* src = (const bfv8*)(V + (size_t)tid*CH);
#pragma unroll
    for (int i=0;i<12;++i){ bfv8 v8 = src[i];
#pragma unroll
      for (int j=0;j<8;++j) vt2[(i*8+j)*264 + tid] = v8[j]; }
  }
  __syncthreads();
  for (int c = wid; c < CH; c += 4)
    *(bfv4*)(V + c*WID + lane*4) = *(const bfv4*)(vt2 + c*264 + lane*4);
}

// ---------------- K_attn: fused scores+softmax+apply, both directions ----------------
__global__ __launch_bounds__(256) void k_attn(
    const bf* __restrict__ Ql, const bf* __restrict__ Qr,
    const bf* __restrict__ Vlt, const bf* __restrict__ Vrt,
    bf* __restrict__ Fout)
{
  extern __shared__ char sm[];
  bf* aq = (bf*)sm;                       // [64][264]
  float* rs = (float*)(sm + 64*264*2);    // [256]
  const int tid=threadIdx.x, lane=tid&63, wid=tid>>6;
  const int l15=lane&15, lg=lane>>4;
  const int bh = blockIdx.x;
  const size_t qoff = (size_t)bh * (WID*CH);
  float fw[16];

#pragma unroll 1
  for (int phase=0; phase<2; ++phase) {
    const bf* msrc = phase ? Qr + qoff : Ql + qoff;
    const bf* nsrc = phase ? Ql + qoff : Qr + qoff;
    const bf* vt   = (phase ? Vlt : Vrt) + qoff;
    const int outoff = phase ? CH : 0;
    if (phase) {
      __syncthreads();
#pragma unroll
      for (int nt=0;nt<16;++nt) fw[nt] = SCALE / rs[nt*16+l15];
    }
#pragma unroll 1
    for (int q=0;q<4;++q) {
      const int m0 = q*64 + wid*16;
      bfv8 af[3];
#pragma unroll
      for (int ks=0;ks<3;++ks)
        af[ks] = *(const bfv8*)(msrc + (size_t)(m0+l15)*CH + ks*32 + lg*8);
      f32x4 acc[16];
#pragma unroll
      for (int nt=0;nt<16;++nt) acc[nt]=(f32x4){0.f,0.f,0.f,0.f};
#pragma unroll
      for (int ks=0;ks<3;++ks)
#pragma unroll
        for (int nt=0;nt<16;++nt)
          acc[nt] = MFMA16(af[ks],
              *(const bfv8*)(nsrc + (size_t)(nt*16+l15)*CH + ks*32+lg*8), acc[nt]);
      if (phase==0) {
        float rsum[4]={0.f,0.f,0.f,0.f};
#pragma unroll
        for (int nt=0;nt<16;++nt)
#pragma unroll
          for (int r=0;r<4;++r){ float e=__expf(acc[nt][r]); acc[nt][r]=e; rsum[r]+=e; }
#pragma unroll
        for (int off=1; off<16; off<<=1)
#pragma unroll
          for (int r=0;r<4;++r) rsum[r] += __shfl_xor(rsum[r], off, 64);
        if (l15==0){
#pragma unroll
          for (int r=0;r<4;++r) rs[m0 + lg*4 + r] = rsum[r];
        }
        float sc[4];
#pragma unroll
        for (int r=0;r<4;++r) sc[r] = SCALE / rsum[r];
#pragma unroll
        for (int nt=0;nt<16;++nt)
#pragma unroll
          for (int r=0;r<4;++r)
            aq[(wid*16+lg*4+r)*264 + nt*16+l15] = f2b(acc[nt][r]*sc[r]);
      } else {
#pragma unroll
        for (int nt=0;nt<16;++nt)
#pragma unroll
          for (int r=0;r<4;++r)
            aq[(wid*16+lg*4+r)*264 + nt*16+l15] = f2b(__expf(acc[nt][r])*fw[nt]);
      }
      f32x4 o[6];
#pragma unroll
      for (int nt=0;nt<6;++nt) o[nt]=(f32x4){0.f,0.f,0.f,0.f};
#pragma unroll
      for (int ks=0;ks<8;++ks) {
        bfv8 aa = *(const bfv8*)(aq + (wid*16+l15)*264 + ks*32 + lg*8);
#pragma unroll
        for (int nt=0;nt<6;++nt)
          o[nt] = MFMA16(aa,
              *(const bfv8*)(vt + (size_t)(nt*16+l15)*WID + ks*32+lg*8), o[nt]);
      }
#pragma unroll
      for (int nt=0;nt<6;++nt){
        int c = nt*16+l15;
#pragma unroll
        for (int r=0;r<4;++r){
          size_t p = (size_t)bh*WID + m0 + lg*4 + r;
          Fout[p*192 + outoff + c] = f2b(o[nt][r]);
        }
      }
    }
  }
}

// ---------------- K_wprep: fold lp2/beta/rp2/gamma/down into Wcat[96][384] + b'[96] ----------------
__global__ __launch_bounds__(256) void k_wprep(
    const float* __restrict__ L, const float* __restrict__ lb,
    const float* __restrict__ R, const float* __restrict__ rb,
    const float* __restrict__ D, const float* __restrict__ db,
    const float* __restrict__ beta, const float* __restrict__ gamma,
    bf* __restrict__ Wcat, float* __restrict__ bv)
{
  const int o = blockIdx.x;           // output channel 0..95
  const int tid = threadIdx.x;
  for (int k = tid; k < 384; k += 256){
    float v;
    if (k < 192) v = D[o*192 + k];
    else if (k < 288){
      int c = k - 192; float s = 0.f;
      for (int m=0;m<96;++m) s += D[o*192+m]*beta[m]*L[m*96+c];
      v = s;
    } else {
      int c = k - 288; float s = 0.f;
      for (int m=0;m<96;++m) s += D[o*192+96+m]*gamma[m]*R[m*96+c];
      v = s;
    }
    Wcat[o*384+k] = f2b(v);
  }
  if (tid == 0){
    float s = db[o];
    for (int m=0;m<96;++m) s += D[o*192+m]*beta[m]*lb[m] + D[o*192+96+m]*gamma[m]*rb[m];
    bv[o] = s;
  }
}

// ---------------- K3: out = [x_l | x_r | F1 | F2] @ Wcat + b'  (single K=384 GEMM) ----------------
// 128 px/block; F snapshot in LDS [128][200] = 51,200 B (race-free vs OUT overwrite).
// Wave wv: pair=wv>>1 owns m-tiles pair*4..+3; half=wv&1 owns output cols half*48..+47.
__global__ __launch_bounds__(256) void k_fuse(
    const float* __restrict__ I1, const float* __restrict__ I2,
    const bf* F, const bf* __restrict__ Wcat, const float* __restrict__ bv,
    float* OUT)
{
  extern __shared__ bf fls[];   // [128][200]
  const int tid=threadIdx.x, lane=tid&63, wv=tid>>6;
  const int l15=lane&15, lg=lane>>4;
  const int half = wv&1, pair = wv>>1;
  const size_t p0 = (size_t)blockIdx.x * 128;

  { // stage F -> LDS snapshot
    const int row = tid>>1, seg = (tid&1)*96;
    const bf* fsrc = F + (p0+row)*192 + seg;
    bf* ldst = fls + row*200 + seg;
#pragma unroll
    for (int i=0;i<12;++i) *(bfv8*)(ldst + i*8) = *(const bfv8*)(fsrc + i*8);
  }

  bfv8 wf[12][3];
  float bias[3];
#pragma unroll
  for (int j=0;j<3;++j){
    int c = (half*3+j)*16 + l15;
    bias[j] = bv[c];
#pragma unroll
    for (int kb=0;kb<12;++kb)
      wf[kb][j] = *(const bfv8*)(Wcat + (size_t)c*384 + kb*32 + lg*8);
  }
  __syncthreads();

#pragma unroll
  for (int i=0;i<4;++i){
    const int mloc = (pair*4+i)*16;
    const size_t m0 = p0 + mloc;
    bfv8 a[12];
    const float* x1 = I1 + (m0+l15)*CH + lg*8;
    const float* x2 = I2 + (m0+l15)*CH + lg*8;
    const bf* fp = fls + (mloc+l15)*200 + lg*8;
#pragma unroll
    for (int ks=0;ks<3;++ks){
      a[ks]   = ld_cvt8(x1 + ks*32);
      a[3+ks] = ld_cvt8(x2 + ks*32);
      a[6+ks] = *(const bfv8*)(fp + ks*32);
      a[9+ks] = *(const bfv8*)(fp + 96 + ks*32);
    }
    f32x4 acc[3];
#pragma unroll
    for (int j=0;j<3;++j) acc[j]=(f32x4){bias[j],bias[j],bias[j],bias[j]};
#pragma unroll
    for (int kb=0;kb<12;++kb)
#pragma unroll
      for (int j=0;j<3;++j)
        acc[j] = MFMA16(a[kb], wf[kb][j], acc[j]);
#pragma unroll
    for (int j=0;j<3;++j){
      int c = (half*3+j)*16 + l15;
#pragma unroll
      for (int r=0;r<4;++r)
        OUT[(m0+lg*4+r)*CH + c] = acc[j][r];
    }
  }
}

extern "C" void kernel_launch(void* const* d_in, const int* in_sizes, int n_in,
                              void* d_out, int out_size, void* d_ws, size_t ws_size,
                              hipStream_t stream)
{
  (void)in_sizes; (void)n_in; (void)out_size; (void)ws_size;
  const float* I1 = (const float*)d_in[0];
  const float* I2 = (const float*)d_in[1];
  const float* se1_w = (const float*)d_in[4];
  const float* se1_b = (const float*)d_in[5];
  const float* se1_dw= (const float*)d_in[6];
  const float* se1_db= (const float*)d_in[7];
  const float* se2_w = (const float*)d_in[8];
  const float* se2_b = (const float*)d_in[9];
  const float* se2_dw= (const float*)d_in[10];
  const float* se2_db= (const float*)d_in[11];
  const float* lp1_w = (const float*)d_in[12];
  const float* lp1_b = (const float*)d_in[13];
  const float* lp1_dw= (const float*)d_in[14];
  const float* lp1_db= (const float*)d_in[15];
  const float* rp1_w = (const float*)d_in[16];
  const float* rp1_b = (const float*)d_in[17];
  const float* rp1_dw= (const float*)d_in[18];
  const float* rp1_db= (const float*)d_in[19];
  const float* lp2_w = (const float*)d_in[20];
  const float* lp2_b = (const float*)d_in[21];
  const float* rp2_w = (const float*)d_in[22];
  const float* rp2_b = (const float*)d_in[23];
  const float* down_w= (const float*)d_in[24];
  const float* down_b= (const float*)d_in[25];
  const float* beta  = (const float*)d_in[26];
  const float* gamma = (const float*)d_in[27];
  float* OUT = (float*)d_out;
  bf* Fbuf = (bf*)d_out;   // interleaved F [p][192] bf16, exactly fills out buffer

  const size_t FIELD = (size_t)NB * HGT * WID * CH;
  bf* Ql = (bf*)d_ws;
  bf* Qr = Ql + FIELD;
  bf* Vl = Qr + FIELD;     // becomes Vl^T after k_vt
  bf* Vr = Vl + FIELD;     // becomes Vr^T
  bf* Wcat = Vr + FIELD;               // 96*384 bf16
  float* bv = (float*)(Wcat + 96*384); // 96 f32

  dim3 blk(256,1,1);
  k_wprep<<<dim3(96,1,1), blk, 0, stream>>>(lp2_w, lp2_b, rp2_w, rp2_b,
        down_w, down_b, beta, gamma, Wcat, bv);
  k_proj2<<<dim3(4,128,NB), blk, HROWS*TSTR*2, stream>>>(I1,
        se1_w, se1_b, se1_dw, se1_db, Ql,
        lp1_w, lp1_b, lp1_dw, lp1_db, Vl);
  k_proj2<<<dim3(4,128,NB), blk, HROWS*TSTR*2, stream>>>(I2,
        se2_w, se2_b, se2_dw, se2_db, Qr,
        rp1_w, rp1_b, rp1_dw, rp1_db, Vr);
  k_vt<<<dim3(NB*HGT,2,1), blk, 0, stream>>>(Vl, Vr);
  k_attn<<<dim3(NB*HGT,1,1), blk, 64*264*2 + 256*4, stream>>>(Ql, Qr, Vl, Vr, Fbuf);
  k_fuse<<<dim3(4096,1,1), blk, 128*200*2, stream>>>(I1, I2, Fbuf, Wcat, bv, OUT);
}